// Round 5
// baseline (86.049 us; speedup 1.0000x reference)
//
#include <hip/hip_runtime.h>

// FHE BSGS: out[b,s] = sum_{t=0..15} x[b,(s+2^t)&0xFFFF] * diag[t,s], rolled by 32768.
// Roll by S/2 on the 2^16 ring == store to column s ^ 0x8000 (coalesced).
//
// v11: cut request bytes AND L2 pollution at UNCHANGED total thread count.
// Evidence trail: v7 (2x waves, fixed bytes) neutral; v8/v9 (-15% bytes, half the
// threads) regressed; v10 (-15% bytes, threads kept) mildly helped. Model: after
// the 268 MB scrub, requests are served at a flat ~6 TB/s (HBM/L3 rate) because
// the diag+out streams evict x from each 4 MB L2. Levers: bytes + L2 pollution.
//   - Block = 8 rows x 1024 cols, 512 threads (grid 512x512: total threads
//     identical to v10's 1024x256). diag staged in LDS, shared by 8 rows:
//     diag requests 67 -> 33.5 MB. Total 201 -> 164 MB (-18%).
//   - Per-XCD diag stream halves (4.2 MB/iter); group y pinned to XCD y (bid&7),
//     so the group's 8 x-rows (2 MB) can stay L2-resident.
//   - out stores non-temporal (write-once): stop evicting x from L2.
//   - 20 big-shift loads pre-issued before LDS staging: HBM latency hides under
//     the staging + barrier.
// LDS 128 KB (strip 64 + diag 64) -> 1 block/CU, 8 waves/CU (v7: enough waves).

#define SLOTS 65536
#define MASK  65535
#define NBR   8       // batch rows per block
#define TILEW 1024    // columns per block
#define STRIPW 2048   // TILEW + 1024 lookahead (covers shifts 1..1024)

typedef __attribute__((ext_vector_type(4))) float f4v;

__device__ __forceinline__ void ntstore4(float* p, const float4 v) {
    f4v t = {v.x, v.y, v.z, v.w};
    __builtin_nontemporal_store(t, (f4v*)p);
}

__global__ __launch_bounds__(512) void bsgs_kernel(
    const float* __restrict__ x,
    const float* __restrict__ diag,
    float* __restrict__ out)
{
    __shared__ float  sstrip[NBR][STRIPW];     // 64 KB: x[row][(J+i)&MASK], i<2048
    __shared__ float4 sdiag[16][TILEW / 4];    // 64 KB: diag[t][J + c4*4 .. +3]

    const int bid  = blockIdx.x;       // 0..511
    const int y    = bid & 7;          // batch group == XCD (bid%8 round-robin)
    const int xidx = bid >> 3;         // column tile 0..63
    const int tid  = threadIdx.x;      // 0..511
    const int c4   = tid & 255;        // f4-column within tile
    const int rp   = tid >> 8;         // 0/1 -> this thread owns rows rp*4..rp*4+3
    const int J    = xidx * TILEW;
    const int j    = J + c4 * 4;
    const int bg   = y * NBR;
    const int r0   = rp * 4;

    // (1) big shifts t=11..15 for this thread's 4 rows -- issued FIRST so the
    // HBM/L3 latency flies under the LDS staging and the barrier.
    float4 vd[4][5];
#pragma unroll
    for (int q = 0; q < 4; ++q) {
        const float* __restrict__ xr = x + (size_t)(bg + r0 + q) * SLOTS;
#pragma unroll
        for (int t = 11; t < 16; ++t)
            vd[q][t - 11] = *(const float4*)(xr + ((j + (1 << t)) & MASK));
    }

    // (2) stage diag: thread handles t = 2*tt + rp, its own c4. Coalesced, once
    // per block -> shared by all 8 rows.
#pragma unroll
    for (int tt = 0; tt < 8; ++tt) {
        const int t = tt * 2 + rp;
        sdiag[t][c4] = *(const float4*)(diag + t * SLOTS + J + c4 * 4);
    }

    // (3) stage strips: 1 f4 per (thread, row); 512 threads cover 2048 floats.
#pragma unroll
    for (int r = 0; r < NBR; ++r) {
        const float* __restrict__ xr = x + (size_t)(bg + r) * SLOTS;
        *(float4*)(&sstrip[r][tid * 4]) =
            *(const float4*)(xr + ((J + tid * 4) & MASK));
    }
    __syncthreads();   // the only barrier

    float4 acc[4];
#pragma unroll
    for (int q = 0; q < 4; ++q) acc[q] = make_float4(0.f, 0.f, 0.f, 0.f);

    // t=0..2 (shifts 1,2,4) from per-row v0/w4 slides.
    {
        float4 v0[4], w4[4];
#pragma unroll
        for (int q = 0; q < 4; ++q) {
            const float* sp = &sstrip[r0 + q][c4 * 4];
            v0[q] = *(const float4*)(sp);
            w4[q] = *(const float4*)(sp + 4);
        }
        const float4 d0 = sdiag[0][c4];
        const float4 d1 = sdiag[1][c4];
        const float4 d2 = sdiag[2][c4];
#pragma unroll
        for (int q = 0; q < 4; ++q) {
            acc[q].x += v0[q].y * d0.x + v0[q].z * d1.x + w4[q].x * d2.x;
            acc[q].y += v0[q].z * d0.y + v0[q].w * d1.y + w4[q].y * d2.y;
            acc[q].z += v0[q].w * d0.z + w4[q].x * d1.z + w4[q].z * d2.z;
            acc[q].w += w4[q].x * d0.w + w4[q].y * d1.w + w4[q].w * d2.w;
        }
    }

    // t=3..10 (shifts 8..1024): aligned conflict-free b128 strip reads.
#pragma unroll
    for (int t = 3; t <= 10; ++t) {
        const float4 d = sdiag[t][c4];
#pragma unroll
        for (int q = 0; q < 4; ++q) {
            const float4 v = *(const float4*)(&sstrip[r0 + q][c4 * 4 + (1 << t)]);
            acc[q].x += v.x * d.x; acc[q].y += v.y * d.y;
            acc[q].z += v.z * d.z; acc[q].w += v.w * d.w;
        }
    }

    // t=11..15: the pre-issued global loads.
#pragma unroll
    for (int t = 11; t < 16; ++t) {
        const float4 d = sdiag[t][c4];
#pragma unroll
        for (int q = 0; q < 4; ++q) {
            const float4 v = vd[q][t - 11];
            acc[q].x += v.x * d.x; acc[q].y += v.y * d.y;
            acc[q].z += v.z * d.z; acc[q].w += v.w * d.w;
        }
    }

    // roll by 32768 == XOR top column bit; stores stay coalesced.
    // NT: out is write-once -- keep it from evicting x in L2.
#pragma unroll
    for (int q = 0; q < 4; ++q)
        ntstore4(out + (size_t)(bg + r0 + q) * SLOTS + (j ^ 32768), acc[q]);
}

extern "C" void kernel_launch(void* const* d_in, const int* in_sizes, int n_in,
                              void* d_out, int out_size, void* d_ws, size_t ws_size,
                              hipStream_t stream) {
    const float* x    = (const float*)d_in[0];   // (64, 65536) fp32
    const float* diag = (const float*)d_in[1];   // (16, 65536) fp32
    float* out        = (float*)d_out;           // (64, 65536) fp32
    // d_in[2] = stride (1), d_in[3] = reps (1) -- compile-time constants here.

    bsgs_kernel<<<dim3(512), dim3(512), 0, stream>>>(x, diag, out);
}